// Round 4
// baseline (327.791 us; speedup 1.0000x reference)
//
#include <hip/hip_runtime.h>

// Problem constants
#define G_GRAPHS 1024
#define N_NODES  40
#define M_EDGES  780          // N*(N-1)/2
#define NUM_NODES (G_GRAPHS * N_NODES)          // 40960
#define H_ELEMS  (NUM_NODES * 64)               // 2621440
#define X_STRIDE 160
#define X_PER_G  25600
#define SLOPE 0.1f

#define EDGE_BLOCKS 6240      // 798720 / 128
#define VP_BLOCKS   320       // 40960 / 128
#define PACK_PER_MLP 9216     // W0(4096) + W1(4096) + W2(1024) bf16 elems

typedef __bf16 bf16x8 __attribute__((ext_vector_type(8)));
typedef unsigned short us8 __attribute__((ext_vector_type(8)));
typedef float f32x4 __attribute__((ext_vector_type(4)));

__device__ __forceinline__ float lrelu(float v) { return fmaxf(v, SLOPE * v); }
__device__ __forceinline__ unsigned short f2bf(float x) {
    __bf16 b = (__bf16)x;                       // RNE convert
    return __builtin_bit_cast(unsigned short, b);
}

// ---------------------------------------------------------------------------
// K0: pack MLP weights into MFMA B-fragment order (bf16) in d_ws.
// (unchanged from round 3)
// ---------------------------------------------------------------------------
__global__ __launch_bounds__(256) void k_prep(const float* __restrict__ We0,
                                              const float* __restrict__ We1,
                                              const float* __restrict__ We2,
                                              const float* __restrict__ Wn0,
                                              const float* __restrict__ Wn1,
                                              const float* __restrict__ Wn2,
                                              unsigned short* __restrict__ wp) {
    int t = blockIdx.x * 256 + threadIdx.x;     // 0..18431 (72 blocks)
    int mlp = t / PACK_PER_MLP;
    int o = t - mlp * PACK_PER_MLP;
    const float* W0 = mlp ? Wn0 : We0;
    const float* W1 = mlp ? Wn1 : We1;
    const float* W2 = mlp ? Wn2 : We2;
    float val;
    if (o < 8192) {
        const float* W = (o < 4096) ? W0 : W1;
        int idx = o & 4095;
        int j = idx & 7, l = (idx >> 3) & 63, tt = idx >> 9;   // tt = nt*2+kt
        int kt = tt & 1, nt = tt >> 1;
        int k = kt * 32 + ((l >> 4) & 3) * 8 + j;
        int n = nt * 16 + (l & 15);
        val = W[k * 64 + n];
    } else {
        int idx = o - 8192;                      // 0..1023, nt=0 only
        int j = idx & 7, l = (idx >> 3) & 63, kt = idx >> 9;
        int k = kt * 32 + ((l >> 4) & 3) * 8 + j;
        int n = l & 15;
        val = (n < 10) ? W2[k * 10 + n] : 0.f;
    }
    wp[mlp * PACK_PER_MLP + o] = f2bf(val);
}

// ---------------------------------------------------------------------------
// K1 v3: 3-layer GCN, ONE WAVE PER GRAPH, zero LDS, zero barriers.
// Lane = node (40 active of 64, idle lanes hold zeros). Node features live
// entirely in registers; weights are wave-uniform compile-time-indexed
// (-> s_load + SGPR-operand v_fma). Per-graph column sums via __shfl_xor
// butterfly over 64 lanes. deg==39 => agg = (colsum - own)/39 + b.
// Layer 3 split into two 32-col halves to cap live VGPRs (~72).
// ---------------------------------------------------------------------------
__global__ __launch_bounds__(256) void k_gcn(const float* __restrict__ x,
                                             const float* __restrict__ Wg0,
                                             const float* __restrict__ bg0,
                                             const float* __restrict__ Wg1,
                                             const float* __restrict__ bg1,
                                             const float* __restrict__ Wg2,
                                             const float* __restrict__ bg2,
                                             float* __restrict__ hout) {
    const int lane = threadIdx.x & 63;
    const int wv   = threadIdx.x >> 6;
    const int g    = blockIdx.x * 4 + wv;       // 256 blocks x 4 waves = 1024
    const int n    = lane;
    const bool act = (n < N_NODES);
    const float inv39 = 1.0f / 39.0f;

    // load x[:, :6] for this lane's node (idle lanes: zeros)
    float h0[6];
#pragma unroll
    for (int f = 0; f < 6; f++) h0[f] = 0.f;
    if (act) {
        const float* xr = x + (g * N_NODES + n) * 16;
#pragma unroll
        for (int f = 0; f < 6; f++) h0[f] = xr[f];
    }

    // ---- layer 0: z = h0 @ Wg0 (6x32), agg, lrelu ----
    float h1[32];
    {
        float z[32];
#pragma unroll
        for (int c = 0; c < 32; c++) {
            float s = 0.f;
#pragma unroll
            for (int f = 0; f < 6; f++) s += h0[f] * Wg0[f * 32 + c];
            z[c] = s;
        }
#pragma unroll
        for (int c = 0; c < 32; c++) {
            float own = z[c], s = own;
#pragma unroll
            for (int st = 1; st < 64; st <<= 1) s += __shfl_xor(s, st, 64);
            float v = (s - own) * inv39 + bg0[c];
            h1[c] = act ? lrelu(v) : 0.f;       // idle lanes must stay 0
        }
    }

    // ---- layer 1: z = h1 @ Wg1 (32x32), agg, lrelu ----
    float h2[32];
    {
        float z[32];
#pragma unroll
        for (int c = 0; c < 32; c++) {
            float s = 0.f;
#pragma unroll
            for (int m = 0; m < 32; m++) s += h1[m] * Wg1[m * 32 + c];
            z[c] = s;
        }
#pragma unroll
        for (int c = 0; c < 32; c++) {
            float own = z[c], s = own;
#pragma unroll
            for (int st = 1; st < 64; st <<= 1) s += __shfl_xor(s, st, 64);
            float v = (s - own) * inv39 + bg1[c];
            h2[c] = act ? lrelu(v) : 0.f;
        }
    }

    // ---- layer 2: z = h2 @ Wg2 (32x64), agg, linear; two 32-col halves ----
#pragma unroll
    for (int half = 0; half < 2; half++) {
        float z[32];
#pragma unroll
        for (int c = 0; c < 32; c++) {
            float s = 0.f;
#pragma unroll
            for (int m = 0; m < 32; m++) s += h2[m] * Wg2[m * 64 + half * 32 + c];
            z[c] = s;
        }
#pragma unroll
        for (int c = 0; c < 32; c++) {
            float own = z[c], s = own;
#pragma unroll
            for (int st = 1; st < 64; st <<= 1) s += __shfl_xor(s, st, 64);
            z[c] = (s - own) * inv39 + bg2[half * 32 + c];
        }
        if (act) {
            float4* dst = (float4*)(hout + (g * N_NODES + n) * 64 + half * 32);
#pragma unroll
            for (int q = 0; q < 8; q++)
                dst[q] = make_float4(z[4 * q + 0], z[4 * q + 1],
                                     z[4 * q + 2], z[4 * q + 3]);
        }
    }
}

// ---------------------------------------------------------------------------
// K2: fused node+edge MLP via bf16 MFMA (16x16x32), 128 rows/block,
// fully wave-local (no __syncthreads). (unchanged from round 3)
// ---------------------------------------------------------------------------
__global__ __launch_bounds__(256) void k_mlp(const float* __restrict__ h,
                                             const unsigned short* __restrict__ wp,
                                             const float* __restrict__ be0,
                                             const float* __restrict__ be1,
                                             const float* __restrict__ be2,
                                             const float* __restrict__ bn0,
                                             const float* __restrict__ bn1,
                                             const float* __restrict__ bn2,
                                             float* __restrict__ X) {
    __shared__ __align__(16) unsigned short sE[128 * 64];   // E, later Z2
    __shared__ __align__(16) unsigned short sZ[128 * 64];   // Z1
    __shared__ __align__(16) float sEP[128 * 12];           // ep (10 used)

    const int tid = threadIdx.x;
    const int l = tid & 63;          // lane
    const int w = tid >> 6;          // wave 0..3
    const int bid = blockIdx.x;
    const bool is_edge = (bid < EDGE_BLOCKS);

    const unsigned short* wb = wp + (is_edge ? 0 : PACK_PER_MLP);
    const float* b0 = is_edge ? be0 : bn0;
    const float* b1 = is_edge ? be1 : bn1;
    const float* b2 = is_edge ? be2 : bn2;

    const int r = 32 * w + (l >> 1);   // this thread's row (E-build & scatter)
    const int hf = l & 1;              // feature half / scatter role
    int g, i = 0, j = 0;
    if (is_edge) {
        int eid = bid * 128 + r;
        g = eid / M_EDGES;
        int m = eid - g * M_EDGES;
        int rem = m;
        while (rem >= (N_NODES - 1) - i) { rem -= (N_NODES - 1) - i; ++i; }
        j = i + 1 + rem;
    } else {
        int nid = (bid - EDGE_BLOCKS) * 128 + r;
        g = nid / N_NODES;
        i = nid - g * N_NODES;
        j = i;
    }

    // ---- E build: row r, features [hf*32, hf*32+32) ----
    {
        const float4* pa = (const float4*)(h + (g * N_NODES + i) * 64 + hf * 32);
        const float4* pb = (const float4*)(h + (g * N_NODES + j) * 64 + hf * 32);
        unsigned short tmp[32];
#pragma unroll
        for (int q = 0; q < 8; q++) {
            float4 a = pa[q];
            if (is_edge) {
                float4 b = pb[q];
                a.x += b.x; a.y += b.y; a.z += b.z; a.w += b.w;
            }
            tmp[4 * q + 0] = f2bf(a.x); tmp[4 * q + 1] = f2bf(a.y);
            tmp[4 * q + 2] = f2bf(a.z); tmp[4 * q + 3] = f2bf(a.w);
        }
#pragma unroll
        for (int q = 0; q < 4; q++) {
            int cs = (hf * 4 + q) ^ (r & 7);
            *(us8*)((char*)sE + r * 128 + cs * 16) = *(const us8*)(tmp + 8 * q);
        }
    }

    const int col0 = l & 15, rq = (l >> 4) & 3;

    // A-fragment loader: A[m=lane&15][k=(lane>>4)*8+j]
    auto Afrag = [&](const unsigned short* s, int mt, int kt) -> bf16x8 {
        int row = 32 * w + mt * 16 + col0;
        int cs = (kt * 4 + rq) ^ (row & 7);
        return __builtin_bit_cast(bf16x8,
            *(const us8*)((const char*)s + row * 128 + cs * 16));
    };
    auto Bfrag = [&](const unsigned short* base, int tt) -> bf16x8 {
        return __builtin_bit_cast(bf16x8, *(const us8*)(base + (tt * 64 + l) * 8));
    };

    // ---- GEMM1: Z1 = lrelu(E @ W0 + b0), bf16 -> sZ ----
    {
        bf16x8 A[2][2];
#pragma unroll
        for (int mt = 0; mt < 2; mt++)
#pragma unroll
            for (int kt = 0; kt < 2; kt++) A[mt][kt] = Afrag(sE, mt, kt);
        f32x4 acc[2][4];
#pragma unroll
        for (int mt = 0; mt < 2; mt++)
#pragma unroll
            for (int nt = 0; nt < 4; nt++) acc[mt][nt] = (f32x4){0.f, 0.f, 0.f, 0.f};
#pragma unroll
        for (int nt = 0; nt < 4; nt++) {
            bf16x8 B0 = Bfrag(wb, nt * 2 + 0), B1 = Bfrag(wb, nt * 2 + 1);
#pragma unroll
            for (int mt = 0; mt < 2; mt++) {
                acc[mt][nt] = __builtin_amdgcn_mfma_f32_16x16x32_bf16(A[mt][0], B0, acc[mt][nt], 0, 0, 0);
                acc[mt][nt] = __builtin_amdgcn_mfma_f32_16x16x32_bf16(A[mt][1], B1, acc[mt][nt], 0, 0, 0);
            }
        }
#pragma unroll
        for (int nt = 0; nt < 4; nt++) {
            float bi = b0[nt * 16 + col0];
#pragma unroll
            for (int mt = 0; mt < 2; mt++)
#pragma unroll
                for (int reg = 0; reg < 4; reg++) {
                    int row = 32 * w + mt * 16 + rq * 4 + reg;
                    int col = nt * 16 + col0;
                    float z = lrelu(acc[mt][nt][reg] + bi);
                    int cs = (col >> 3) ^ (row & 7);
                    *(unsigned short*)((char*)sZ + row * 128 + cs * 16 + (col & 7) * 2) = f2bf(z);
                }
        }
    }

    // ---- GEMM2: Z2 = lrelu(Z1 @ W1 + b1), bf16 -> sE (reuse) ----
    {
        bf16x8 A[2][2];
#pragma unroll
        for (int mt = 0; mt < 2; mt++)
#pragma unroll
            for (int kt = 0; kt < 2; kt++) A[mt][kt] = Afrag(sZ, mt, kt);
        f32x4 acc[2][4];
#pragma unroll
        for (int mt = 0; mt < 2; mt++)
#pragma unroll
            for (int nt = 0; nt < 4; nt++) acc[mt][nt] = (f32x4){0.f, 0.f, 0.f, 0.f};
        const unsigned short* w1p = wb + 4096;
#pragma unroll
        for (int nt = 0; nt < 4; nt++) {
            bf16x8 B0 = Bfrag(w1p, nt * 2 + 0), B1 = Bfrag(w1p, nt * 2 + 1);
#pragma unroll
            for (int mt = 0; mt < 2; mt++) {
                acc[mt][nt] = __builtin_amdgcn_mfma_f32_16x16x32_bf16(A[mt][0], B0, acc[mt][nt], 0, 0, 0);
                acc[mt][nt] = __builtin_amdgcn_mfma_f32_16x16x32_bf16(A[mt][1], B1, acc[mt][nt], 0, 0, 0);
            }
        }
#pragma unroll
        for (int nt = 0; nt < 4; nt++) {
            float bi = b1[nt * 16 + col0];
#pragma unroll
            for (int mt = 0; mt < 2; mt++)
#pragma unroll
                for (int reg = 0; reg < 4; reg++) {
                    int row = 32 * w + mt * 16 + rq * 4 + reg;
                    int col = nt * 16 + col0;
                    float z = lrelu(acc[mt][nt][reg] + bi);
                    int cs = (col >> 3) ^ (row & 7);
                    *(unsigned short*)((char*)sE + row * 128 + cs * 16 + (col & 7) * 2) = f2bf(z);
                }
        }
    }

    // ---- GEMM3: EP = Z2 @ W2 + b2 (cols 0..9), fp32 -> sEP ----
    {
        bf16x8 A[2][2];
#pragma unroll
        for (int mt = 0; mt < 2; mt++)
#pragma unroll
            for (int kt = 0; kt < 2; kt++) A[mt][kt] = Afrag(sE, mt, kt);
        const unsigned short* w2p = wb + 8192;
        bf16x8 B0 = Bfrag(w2p, 0), B1 = Bfrag(w2p, 1);
        f32x4 acc[2];
#pragma unroll
        for (int mt = 0; mt < 2; mt++) {
            acc[mt] = (f32x4){0.f, 0.f, 0.f, 0.f};
            acc[mt] = __builtin_amdgcn_mfma_f32_16x16x32_bf16(A[mt][0], B0, acc[mt], 0, 0, 0);
            acc[mt] = __builtin_amdgcn_mfma_f32_16x16x32_bf16(A[mt][1], B1, acc[mt], 0, 0, 0);
        }
        if (col0 < 10) {
            float bz = b2[col0];
#pragma unroll
            for (int mt = 0; mt < 2; mt++)
#pragma unroll
                for (int reg = 0; reg < 4; reg++) {
                    int row = 32 * w + mt * 16 + rq * 4 + reg;
                    sEP[row * 12 + col0] = acc[mt][reg] + bz;
                }
        }
    }

    // ---- scatter: SMAT_IDX 4x4 block(s) for this thread's row ----
    {
        const float4* ev = (const float4*)(sEP + r * 12);
        float4 e0 = ev[0], e1 = ev[1], e2 = ev[2];
        float4 r0 = make_float4(e0.x, e0.y, e0.z, e0.w);
        float4 r1 = make_float4(e0.y, e1.x, e1.y, e1.z);
        float4 r2 = make_float4(e0.z, e1.y, e1.w, e2.x);
        float4 r3 = make_float4(e0.w, e1.z, e2.x, e2.y);
        float* Xg = X + g * X_PER_G;
        if (is_edge) {
            int bi = hf ? j : i, bj = hf ? i : j;   // (i,j) and (j,i); block symmetric
            float* p = Xg + (4 * bi) * X_STRIDE + 4 * bj;
            *(float4*)(p + 0 * X_STRIDE) = r0;
            *(float4*)(p + 1 * X_STRIDE) = r1;
            *(float4*)(p + 2 * X_STRIDE) = r2;
            *(float4*)(p + 3 * X_STRIDE) = r3;
        } else {
            float* p = Xg + (4 * i + hf * 2) * X_STRIDE + 4 * i;
            if (hf == 0) {
                *(float4*)(p + 0 * X_STRIDE) = r0;
                *(float4*)(p + 1 * X_STRIDE) = r1;
            } else {
                *(float4*)(p + 0 * X_STRIDE) = r2;
                *(float4*)(p + 1 * X_STRIDE) = r3;
            }
        }
    }
}

// ---------------------------------------------------------------------------
// Launch
// ---------------------------------------------------------------------------
extern "C" void kernel_launch(void* const* d_in, const int* in_sizes, int n_in,
                              void* d_out, int out_size, void* d_ws, size_t ws_size,
                              hipStream_t stream) {
    const float* x   = (const float*)d_in[0];
    const float* Wg0 = (const float*)d_in[4];
    const float* bg0 = (const float*)d_in[5];
    const float* Wg1 = (const float*)d_in[6];
    const float* bg1 = (const float*)d_in[7];
    const float* Wg2 = (const float*)d_in[8];
    const float* bg2 = (const float*)d_in[9];
    const float* Wn0 = (const float*)d_in[10];
    const float* bn0 = (const float*)d_in[11];
    const float* Wn1 = (const float*)d_in[12];
    const float* bn1 = (const float*)d_in[13];
    const float* Wn2 = (const float*)d_in[14];
    const float* bn2 = (const float*)d_in[15];
    const float* We0 = (const float*)d_in[16];
    const float* be0 = (const float*)d_in[17];
    const float* We1 = (const float*)d_in[18];
    const float* be1 = (const float*)d_in[19];
    const float* We2 = (const float*)d_in[20];
    const float* be2 = (const float*)d_in[21];

    float* hout = (float*)d_out;            // h: 40960 x 64 fp32
    float* X    = hout + H_ELEMS;           // X: 1024 x 160 x 160 fp32
    unsigned short* wp = (unsigned short*)d_ws;  // 18432 bf16 packed weights

    k_prep<<<72, 256, 0, stream>>>(We0, We1, We2, Wn0, Wn1, Wn2, wp);
    k_gcn<<<G_GRAPHS / 4, 256, 0, stream>>>(x, Wg0, bg0, Wg1, bg1, Wg2, bg2, hout);
    k_mlp<<<EDGE_BLOCKS + VP_BLOCKS, 256, 0, stream>>>(hout, wp,
                                                       be0, be1, be2,
                                                       bn0, bn1, bn2, X);
}

// Round 5
// 235.878 us; speedup vs baseline: 1.3897x; 1.3897x over previous
//
#include <hip/hip_runtime.h>

// Problem constants
#define G_GRAPHS 1024
#define N_NODES  40
#define M_EDGES  780          // N*(N-1)/2
#define NUM_NODES (G_GRAPHS * N_NODES)          // 40960
#define H_ELEMS  (NUM_NODES * 64)               // 2621440
#define X_STRIDE 160
#define X_PER_G  25600
#define SLOPE 0.1f

#define EDGE_BLOCKS 6240      // 798720 / 128
#define VP_BLOCKS   320       // 40960 / 128
#define PACK_PER_MLP 9216     // W0(4096) + W1(4096) + W2(1024) bf16 elems

typedef __bf16 bf16x8 __attribute__((ext_vector_type(8)));
typedef unsigned short us8 __attribute__((ext_vector_type(8)));
typedef float f32x4 __attribute__((ext_vector_type(4)));

__device__ __forceinline__ float lrelu(float v) { return fmaxf(v, SLOPE * v); }
__device__ __forceinline__ unsigned short f2bf(float x) {
    __bf16 b = (__bf16)x;                       // RNE convert
    return __builtin_bit_cast(unsigned short, b);
}
__device__ __forceinline__ unsigned int pk2bf(float a, float b) {
    return (unsigned int)f2bf(a) | ((unsigned int)f2bf(b) << 16);
}

// ---------------------------------------------------------------------------
// K0: pack MLP weights (bf16) in d_ws. Layout serves BOTH the old B-frag and
// the new A-frag role: element for lane l, reg j, tile (mt,kt) of W^T is
// W[kt*32 + ((l>>4)&3)*8 + j][mt*16 + (l&15)]  -> linear ((mt*2+kt)*64+l)*8+j.
// W2 padded 10->16 cols (zeros). [0..9215] edge MLP, [9216..18431] node MLP.
// ---------------------------------------------------------------------------
__global__ __launch_bounds__(256) void k_prep(const float* __restrict__ We0,
                                              const float* __restrict__ We1,
                                              const float* __restrict__ We2,
                                              const float* __restrict__ Wn0,
                                              const float* __restrict__ Wn1,
                                              const float* __restrict__ Wn2,
                                              unsigned short* __restrict__ wp) {
    int t = blockIdx.x * 256 + threadIdx.x;     // 0..18431 (72 blocks)
    int mlp = t / PACK_PER_MLP;
    int o = t - mlp * PACK_PER_MLP;
    const float* W0 = mlp ? Wn0 : We0;
    const float* W1 = mlp ? Wn1 : We1;
    const float* W2 = mlp ? Wn2 : We2;
    float val;
    if (o < 8192) {
        const float* W = (o < 4096) ? W0 : W1;
        int idx = o & 4095;
        int j = idx & 7, l = (idx >> 3) & 63, tt = idx >> 9;   // tt = mt*2+kt
        int kt = tt & 1, mt = tt >> 1;
        int k = kt * 32 + ((l >> 4) & 3) * 8 + j;
        int m = mt * 16 + (l & 15);
        val = W[k * 64 + m];
    } else {
        int idx = o - 8192;                      // 0..1023, mt=0 only
        int j = idx & 7, l = (idx >> 3) & 63, kt = idx >> 9;
        int k = kt * 32 + ((l >> 4) & 3) * 8 + j;
        int m = l & 15;
        val = (m < 10) ? W2[k * 10 + m] : 0.f;
    }
    wp[mlp * PACK_PER_MLP + o] = f2bf(val);
}

// ---------------------------------------------------------------------------
// K1: 3-layer GCN, one block per graph (round-3 version — reverted; the
// wave-per-graph variant ran at 1 wave/SIMD with spills and regressed).
// deg==39 everywhere => aggregation = (colsum - own)/39 + b.
// ---------------------------------------------------------------------------
__global__ __launch_bounds__(256) void k_gcn(const float* __restrict__ x,
                                             const float* __restrict__ Wg0,
                                             const float* __restrict__ bg0,
                                             const float* __restrict__ Wg1,
                                             const float* __restrict__ bg1,
                                             const float* __restrict__ Wg2,
                                             const float* __restrict__ bg2,
                                             float* __restrict__ hout) {
    __shared__ float h0[N_NODES * 6];
    __shared__ float buf[N_NODES * 64];
    __shared__ float S[64];
    __shared__ float P[8 * 64];
    __shared__ float h1[N_NODES * 32];
    __shared__ float h2[N_NODES * 32];

    const int g = blockIdx.x;
    const int tid = threadIdx.x;
    const float inv39 = 1.0f / 39.0f;

    for (int idx = tid; idx < N_NODES * 6; idx += 256) {
        int n = idx / 6, f = idx - n * 6;
        h0[idx] = x[(g * N_NODES + n) * 16 + f];
    }
    __syncthreads();

    // layer 0
    for (int idx = tid; idx < N_NODES * 32; idx += 256) {
        int n = idx >> 5, c = idx & 31;
        float s = 0.f;
#pragma unroll
        for (int f = 0; f < 6; f++) s += h0[n * 6 + f] * Wg0[f * 32 + c];
        buf[n * 32 + c] = s;
    }
    __syncthreads();
    { int c = tid & 31, grp = tid >> 5; float s = 0.f;
#pragma unroll
      for (int n = grp * 5; n < grp * 5 + 5; n++) s += buf[n * 32 + c];
      P[grp * 32 + c] = s; }
    __syncthreads();
    if (tid < 32) { float s = 0.f;
#pragma unroll
      for (int grp = 0; grp < 8; grp++) s += P[grp * 32 + tid];
      S[tid] = s; }
    __syncthreads();
    for (int idx = tid; idx < N_NODES * 32; idx += 256) {
        int n = idx >> 5, c = idx & 31;
        h1[idx] = lrelu((S[c] - buf[n * 32 + c]) * inv39 + bg0[c]);
    }
    __syncthreads();

    // layer 1
    for (int idx = tid; idx < N_NODES * 32; idx += 256) {
        int n = idx >> 5, c = idx & 31;
        float s = 0.f;
#pragma unroll
        for (int m = 0; m < 32; m++) s += h1[n * 32 + m] * Wg1[m * 32 + c];
        buf[n * 32 + c] = s;
    }
    __syncthreads();
    { int c = tid & 31, grp = tid >> 5; float s = 0.f;
#pragma unroll
      for (int n = grp * 5; n < grp * 5 + 5; n++) s += buf[n * 32 + c];
      P[grp * 32 + c] = s; }
    __syncthreads();
    if (tid < 32) { float s = 0.f;
#pragma unroll
      for (int grp = 0; grp < 8; grp++) s += P[grp * 32 + tid];
      S[tid] = s; }
    __syncthreads();
    for (int idx = tid; idx < N_NODES * 32; idx += 256) {
        int n = idx >> 5, c = idx & 31;
        h2[idx] = lrelu((S[c] - buf[n * 32 + c]) * inv39 + bg1[c]);
    }
    __syncthreads();

    // layer 2
    for (int idx = tid; idx < N_NODES * 64; idx += 256) {
        int n = idx >> 6, c = idx & 63;
        float s = 0.f;
#pragma unroll
        for (int m = 0; m < 32; m++) s += h2[n * 32 + m] * Wg2[m * 64 + c];
        buf[idx] = s;
    }
    __syncthreads();
    { int c = tid & 63, grp = tid >> 6; float s = 0.f;
#pragma unroll
      for (int n = grp * 10; n < grp * 10 + 10; n++) s += buf[n * 64 + c];
      P[grp * 64 + c] = s; }
    __syncthreads();
    if (tid < 64) { float s = 0.f;
#pragma unroll
      for (int grp = 0; grp < 4; grp++) s += P[grp * 64 + tid];
      S[tid] = s; }
    __syncthreads();
    for (int idx = tid; idx < N_NODES * 64; idx += 256) {
        int n = idx >> 6, c = idx & 63;
        hout[(g * N_NODES + n) * 64 + c] = (S[c] - buf[n * 64 + c]) * inv39 + bg2[c];
    }
}

// ---------------------------------------------------------------------------
// K2 v2: fused node+edge MLP, FLIPPED operands: A = W^T (global, packed),
// B = activations^T (LDS). C/D col = node, rows = features -> each lane's
// 4 acc regs are 4 consecutive features of ONE node: epilogue is packed
// ds_write_b64 (8/GEMM) instead of 32 scalar ds_write_u16. B-frag reads are
// contiguous swizzled ds_read_b128. Fully wave-local, no __syncthreads.
// sEP aliased into the wave's own dead Z1 slice (stride 20 floats to break
// bank conflicts). LDS = 32 KB -> up to 5 blocks/CU.
// ---------------------------------------------------------------------------
__global__ __launch_bounds__(256) void k_mlp(const float* __restrict__ h,
                                             const unsigned short* __restrict__ wp,
                                             const float* __restrict__ be0,
                                             const float* __restrict__ be1,
                                             const float* __restrict__ be2,
                                             const float* __restrict__ bn0,
                                             const float* __restrict__ bn1,
                                             const float* __restrict__ bn2,
                                             float* __restrict__ X) {
    __shared__ __align__(16) unsigned short sE[128 * 64];   // E, later Z2
    __shared__ __align__(16) unsigned short sZ[128 * 64];   // Z1, later sEP

    const int tid = threadIdx.x;
    const int l = tid & 63;          // lane
    const int w = tid >> 6;          // wave 0..3
    const int bid = blockIdx.x;
    const bool is_edge = (bid < EDGE_BLOCKS);

    const unsigned short* wb = wp + (is_edge ? 0 : PACK_PER_MLP);
    const float* b0 = is_edge ? be0 : bn0;
    const float* b1 = is_edge ? be1 : bn1;
    const float* b2 = is_edge ? be2 : bn2;

    const int r = 32 * w + (l >> 1);   // this thread's row (E-build & scatter)
    const int hf = l & 1;              // feature half / scatter role
    int g, i = 0, j = 0;
    if (is_edge) {
        int eid = bid * 128 + r;
        g = eid / M_EDGES;
        int m = eid - g * M_EDGES;
        int rem = m;
        while (rem >= (N_NODES - 1) - i) { rem -= (N_NODES - 1) - i; ++i; }
        j = i + 1 + rem;
    } else {
        int nid = (bid - EDGE_BLOCKS) * 128 + r;
        g = nid / N_NODES;
        i = nid - g * N_NODES;
        j = i;
    }

    // ---- E build: row r, features [hf*32, hf*32+32) -> sE (swizzled) ----
    {
        const float4* pa = (const float4*)(h + (g * N_NODES + i) * 64 + hf * 32);
        const float4* pb = (const float4*)(h + (g * N_NODES + j) * 64 + hf * 32);
        unsigned short tmp[32];
#pragma unroll
        for (int q = 0; q < 8; q++) {
            float4 a = pa[q];
            if (is_edge) {
                float4 b = pb[q];
                a.x += b.x; a.y += b.y; a.z += b.z; a.w += b.w;
            }
            tmp[4 * q + 0] = f2bf(a.x); tmp[4 * q + 1] = f2bf(a.y);
            tmp[4 * q + 2] = f2bf(a.z); tmp[4 * q + 3] = f2bf(a.w);
        }
#pragma unroll
        for (int q = 0; q < 4; q++) {
            int cs = (hf * 4 + q) ^ (r & 7);
            *(us8*)((char*)sE + r * 128 + cs * 16) = *(const us8*)(tmp + 8 * q);
        }
    }

    const int nl = l & 15;           // node-within-tile (C/D col & B n-index)
    const int rq = (l >> 4) & 3;

    // A-frag (weights) from global: lane l holds W[k=kt*32+rq*8+j][m=mt*16+nl]
    auto WA = [&](const unsigned short* base, int mt, int kt) -> bf16x8 {
        return __builtin_bit_cast(bf16x8,
            *(const us8*)(base + ((mt * 2 + kt) * 64 + l) * 8));
    };
    // B-frag (activations) from LDS: node fixed, k = kt*32+rq*8+j contiguous
    auto ZB = [&](const unsigned short* s, int nt, int kt) -> bf16x8 {
        int node = 32 * w + nt * 16 + nl;
        int cs = (kt * 4 + rq) ^ (node & 7);
        return __builtin_bit_cast(bf16x8,
            *(const us8*)((const char*)s + node * 128 + cs * 16));
    };
    // packed bf16x2 epilogue write: feats [mt*16+rq*4 .. +4) of node
    auto zstore = [&](unsigned short* s, int mt, int nt, const f32x4& v) {
        int node = 32 * w + nt * 16 + nl;
        int cs = (mt * 2 + (rq >> 1)) ^ (node & 7);
        uint2 u = make_uint2(pk2bf(v[0], v[1]), pk2bf(v[2], v[3]));
        *(uint2*)((char*)s + node * 128 + cs * 16 + (rq & 1) * 8) = u;
    };

    // ---- GEMM1: Z1 = lrelu(E @ W0 + b0) -> sZ ----
    {
        bf16x8 B[2][2];
#pragma unroll
        for (int nt = 0; nt < 2; nt++)
#pragma unroll
            for (int kt = 0; kt < 2; kt++) B[nt][kt] = ZB(sE, nt, kt);
#pragma unroll
        for (int mt = 0; mt < 4; mt++) {
            bf16x8 A0 = WA(wb, mt, 0), A1 = WA(wb, mt, 1);
            float4 bv = *(const float4*)(b0 + mt * 16 + rq * 4);
#pragma unroll
            for (int nt = 0; nt < 2; nt++) {
                f32x4 acc = (f32x4){0.f, 0.f, 0.f, 0.f};
                acc = __builtin_amdgcn_mfma_f32_16x16x32_bf16(A0, B[nt][0], acc, 0, 0, 0);
                acc = __builtin_amdgcn_mfma_f32_16x16x32_bf16(A1, B[nt][1], acc, 0, 0, 0);
                f32x4 z;
                z[0] = lrelu(acc[0] + bv.x); z[1] = lrelu(acc[1] + bv.y);
                z[2] = lrelu(acc[2] + bv.z); z[3] = lrelu(acc[3] + bv.w);
                zstore(sZ, mt, nt, z);
            }
        }
    }

    // ---- GEMM2: Z2 = lrelu(Z1 @ W1 + b1) -> sE (reuse) ----
    {
        bf16x8 B[2][2];
#pragma unroll
        for (int nt = 0; nt < 2; nt++)
#pragma unroll
            for (int kt = 0; kt < 2; kt++) B[nt][kt] = ZB(sZ, nt, kt);
        const unsigned short* w1p = wb + 4096;
#pragma unroll
        for (int mt = 0; mt < 4; mt++) {
            bf16x8 A0 = WA(w1p, mt, 0), A1 = WA(w1p, mt, 1);
            float4 bv = *(const float4*)(b1 + mt * 16 + rq * 4);
#pragma unroll
            for (int nt = 0; nt < 2; nt++) {
                f32x4 acc = (f32x4){0.f, 0.f, 0.f, 0.f};
                acc = __builtin_amdgcn_mfma_f32_16x16x32_bf16(A0, B[nt][0], acc, 0, 0, 0);
                acc = __builtin_amdgcn_mfma_f32_16x16x32_bf16(A1, B[nt][1], acc, 0, 0, 0);
                f32x4 z;
                z[0] = lrelu(acc[0] + bv.x); z[1] = lrelu(acc[1] + bv.y);
                z[2] = lrelu(acc[2] + bv.z); z[3] = lrelu(acc[3] + bv.w);
                zstore(sE, mt, nt, z);
            }
        }
    }

    // ---- GEMM3: EP = Z2 @ W2 + b2 -> sEP (fp32, aliased into own sZ slice,
    //      row stride 20 floats) ----
    float* sEPf = (float*)sZ + w * 1024;       // wave-local 4 KB slice
    {
        bf16x8 B[2][2];
#pragma unroll
        for (int nt = 0; nt < 2; nt++)
#pragma unroll
            for (int kt = 0; kt < 2; kt++) B[nt][kt] = ZB(sE, nt, kt);
        const unsigned short* w2p = wb + 8192;
        bf16x8 A0 = WA(w2p, 0, 0), A1 = WA(w2p, 0, 1);
        float bz[4];
#pragma unroll
        for (int k = 0; k < 4; k++) {
            int f = rq * 4 + k;
            bz[k] = (f < 10) ? b2[f] : 0.f;
        }
#pragma unroll
        for (int nt = 0; nt < 2; nt++) {
            f32x4 acc = (f32x4){0.f, 0.f, 0.f, 0.f};
            acc = __builtin_amdgcn_mfma_f32_16x16x32_bf16(A0, B[nt][0], acc, 0, 0, 0);
            acc = __builtin_amdgcn_mfma_f32_16x16x32_bf16(A1, B[nt][1], acc, 0, 0, 0);
            int nl2 = nt * 16 + nl;              // node within wave (0..31)
            float4 v = make_float4(acc[0] + bz[0], acc[1] + bz[1],
                                   acc[2] + bz[2], acc[3] + bz[3]);
            *(float4*)(sEPf + nl2 * 20 + rq * 4) = v;
        }
    }

    // ---- scatter: SMAT_IDX 4x4 block(s) for this thread's row ----
    {
        const float* ep = sEPf + (r & 31) * 20;
        float4 e0 = *(const float4*)(ep + 0);
        float4 e1 = *(const float4*)(ep + 4);
        float4 e2 = *(const float4*)(ep + 8);
        float4 r0 = make_float4(e0.x, e0.y, e0.z, e0.w);
        float4 r1 = make_float4(e0.y, e1.x, e1.y, e1.z);
        float4 r2 = make_float4(e0.z, e1.y, e1.w, e2.x);
        float4 r3 = make_float4(e0.w, e1.z, e2.x, e2.y);
        float* Xg = X + g * X_PER_G;
        if (is_edge) {
            int bi = hf ? j : i, bj = hf ? i : j;   // (i,j) and (j,i); block symmetric
            float* p = Xg + (4 * bi) * X_STRIDE + 4 * bj;
            *(float4*)(p + 0 * X_STRIDE) = r0;
            *(float4*)(p + 1 * X_STRIDE) = r1;
            *(float4*)(p + 2 * X_STRIDE) = r2;
            *(float4*)(p + 3 * X_STRIDE) = r3;
        } else {
            float* p = Xg + (4 * i + hf * 2) * X_STRIDE + 4 * i;
            if (hf == 0) {
                *(float4*)(p + 0 * X_STRIDE) = r0;
                *(float4*)(p + 1 * X_STRIDE) = r1;
            } else {
                *(float4*)(p + 0 * X_STRIDE) = r2;
                *(float4*)(p + 1 * X_STRIDE) = r3;
            }
        }
    }
}

// ---------------------------------------------------------------------------
// Launch
// ---------------------------------------------------------------------------
extern "C" void kernel_launch(void* const* d_in, const int* in_sizes, int n_in,
                              void* d_out, int out_size, void* d_ws, size_t ws_size,
                              hipStream_t stream) {
    const float* x   = (const float*)d_in[0];
    const float* Wg0 = (const float*)d_in[4];
    const float* bg0 = (const float*)d_in[5];
    const float* Wg1 = (const float*)d_in[6];
    const float* bg1 = (const float*)d_in[7];
    const float* Wg2 = (const float*)d_in[8];
    const float* bg2 = (const float*)d_in[9];
    const float* Wn0 = (const float*)d_in[10];
    const float* bn0 = (const float*)d_in[11];
    const float* Wn1 = (const float*)d_in[12];
    const float* bn1 = (const float*)d_in[13];
    const float* Wn2 = (const float*)d_in[14];
    const float* bn2 = (const float*)d_in[15];
    const float* We0 = (const float*)d_in[16];
    const float* be0 = (const float*)d_in[17];
    const float* We1 = (const float*)d_in[18];
    const float* be1 = (const float*)d_in[19];
    const float* We2 = (const float*)d_in[20];
    const float* be2 = (const float*)d_in[21];

    float* hout = (float*)d_out;            // h: 40960 x 64 fp32
    float* X    = hout + H_ELEMS;           // X: 1024 x 160 x 160 fp32
    unsigned short* wp = (unsigned short*)d_ws;  // 18432 bf16 packed weights

    k_prep<<<72, 256, 0, stream>>>(We0, We1, We2, Wn0, Wn1, Wn2, wp);
    k_gcn<<<G_GRAPHS, 256, 0, stream>>>(x, Wg0, bg0, Wg1, bg1, Wg2, bg2, hout);
    k_mlp<<<EDGE_BLOCKS + VP_BLOCKS, 256, 0, stream>>>(hout, wp,
                                                       be0, be1, be2,
                                                       bn0, bn1, bn2, X);
}